// Round 1
// baseline (1296.398 us; speedup 1.0000x reference)
//
#include <hip/hip_runtime.h>

#define NSMP  8192
#define NDIM  3072
#define NK    64
#define NS    48
#define MK    200   // knots per transform
#define GB    256   // lookup-grid buckets

__device__ __forceinline__ float rcp_fast(float x) { return __builtin_amdgcn_rcpf(x); }
__device__ __forceinline__ int imin(int a, int b) { return a < b ? a : b; }

// ---------------------------------------------------------------------------
// Kernel 1: 64 independent 48x48 QR factorizations (modified Gram-Schmidt).
// ---------------------------------------------------------------------------
__global__ __launch_bounds__(64) void qr_kernel(const float* __restrict__ Araw,
                                                float* __restrict__ Qws) {
  const int k = blockIdx.x;
  const int lane = threadIdx.x;
  const float* Ak = Araw + k * NS * NS;
  float col[NS];
#pragma unroll
  for (int r = 0; r < NS; ++r)
    col[r] = (lane < NS) ? Ak[r * NS + lane] : 0.f;

  for (int j = 0; j < NS; ++j) {
    float q[NS];
#pragma unroll
    for (int r = 0; r < NS; ++r)
      q[r] = __int_as_float(__builtin_amdgcn_readlane(__float_as_int(col[r]), j));
    float n0 = 0.f, n1 = 0.f, n2 = 0.f, n3 = 0.f;
#pragma unroll
    for (int r = 0; r < NS; r += 4) {
      n0 = fmaf(q[r+0], q[r+0], n0); n1 = fmaf(q[r+1], q[r+1], n1);
      n2 = fmaf(q[r+2], q[r+2], n2); n3 = fmaf(q[r+3], q[r+3], n3);
    }
    float rinv = 1.0f / sqrtf((n0 + n1) + (n2 + n3));
#pragma unroll
    for (int r = 0; r < NS; ++r) q[r] *= rinv;
    if (lane == j) {
#pragma unroll
      for (int r = 0; r < NS; ++r) col[r] = q[r];
    } else if (lane > j && lane < NS) {
      float d0 = 0.f, d1 = 0.f, d2 = 0.f, d3 = 0.f;
#pragma unroll
      for (int r = 0; r < NS; r += 4) {
        d0 = fmaf(q[r+0], col[r+0], d0); d1 = fmaf(q[r+1], col[r+1], d1);
        d2 = fmaf(q[r+2], col[r+2], d2); d3 = fmaf(q[r+3], col[r+3], d3);
      }
      float dt = (d0 + d1) + (d2 + d3);
#pragma unroll
      for (int r = 0; r < NS; ++r) col[r] = fmaf(-dt, q[r], col[r]);
    }
  }
  if (lane < NS) {
    float* Qk = Qws + k * NS * NS;
#pragma unroll
    for (int r = 0; r < NS; ++r) Qk[r * NS + lane] = col[r];
  }
}

// ---------------------------------------------------------------------------
// Kernel 2: knot tables. One wave per transform row t.
//  xxg[t][0..199]    knot x positions
//  ydk8[t][kk]       2x float4: (xK, 1/dx, yK, dy), (s, dK, dK1, dK+dK1-2s)
//  edge[t*2+{0,1}]   (xx0,yy0,del0,scale), (xxM,yyM,delM,0)
//  gridb[t][g] u8    start interval for bucket g
// ---------------------------------------------------------------------------
__global__ __launch_bounds__(256) void knots_kernel(
    const float* __restrict__ x0, const float* __restrict__ logdx,
    const float* __restrict__ y0, const float* __restrict__ logdy,
    const float* __restrict__ logderiv,
    float* __restrict__ xxg, float4* __restrict__ ydk8,
    float4* __restrict__ edge, unsigned char* __restrict__ gridb) {
  const int wid = threadIdx.x >> 6, lane = threadIdx.x & 63;
  const int t = blockIdx.x * 4 + wid;
  __shared__ float sxx[4][MK], syy[4][MK], sdel[4][MK];

  {
    const float* row = logdx + t * (MK - 1);
    int i0 = lane * 4;
    float e0 = (i0 + 0 < MK - 1) ? __expf(row[i0 + 0]) : 0.f;
    float e1 = (i0 + 1 < MK - 1) ? __expf(row[i0 + 1]) : 0.f;
    float e2 = (i0 + 2 < MK - 1) ? __expf(row[i0 + 2]) : 0.f;
    float e3 = (i0 + 3 < MK - 1) ? __expf(row[i0 + 3]) : 0.f;
    float p0 = e0, p1 = p0 + e1, p2 = p1 + e2, p3 = p2 + e3;
    float incl = p3;
#pragma unroll
    for (int off = 1; off < 64; off <<= 1) {
      float u = __shfl_up(incl, off, 64);
      if (lane >= off) incl += u;
    }
    float xv = x0[t];
    float base = xv + (incl - p3);
    float* xrow = xxg + t * MK;
    if (lane == 0) { xrow[0] = xv; sxx[wid][0] = xv; }
    if (i0 + 0 < MK - 1) { xrow[1+i0+0] = base + p0; sxx[wid][1+i0+0] = base + p0; }
    if (i0 + 1 < MK - 1) { xrow[1+i0+1] = base + p1; sxx[wid][1+i0+1] = base + p1; }
    if (i0 + 2 < MK - 1) { xrow[1+i0+2] = base + p2; sxx[wid][1+i0+2] = base + p2; }
    if (i0 + 3 < MK - 1) { xrow[1+i0+3] = base + p3; sxx[wid][1+i0+3] = base + p3; }
  }
  {
    const float* row = logdy + t * (MK - 1);
    int i0 = lane * 4;
    float e0 = (i0 + 0 < MK - 1) ? __expf(row[i0 + 0]) : 0.f;
    float e1 = (i0 + 1 < MK - 1) ? __expf(row[i0 + 1]) : 0.f;
    float e2 = (i0 + 2 < MK - 1) ? __expf(row[i0 + 2]) : 0.f;
    float e3 = (i0 + 3 < MK - 1) ? __expf(row[i0 + 3]) : 0.f;
    float p0 = e0, p1 = p0 + e1, p2 = p1 + e2, p3 = p2 + e3;
    float incl = p3;
#pragma unroll
    for (int off = 1; off < 64; off <<= 1) {
      float u = __shfl_up(incl, off, 64);
      if (lane >= off) incl += u;
    }
    float yv = y0[t];
    float base = yv + (incl - p3);
    if (lane == 0) syy[wid][0] = yv;
    if (i0 + 0 < MK - 1) syy[wid][1+i0+0] = base + p0;
    if (i0 + 1 < MK - 1) syy[wid][1+i0+1] = base + p1;
    if (i0 + 2 < MK - 1) syy[wid][1+i0+2] = base + p2;
    if (i0 + 3 < MK - 1) syy[wid][1+i0+3] = base + p3;
  }
  {
    const float* ld = logderiv + t * MK;
#pragma unroll
    for (int rep = 0; rep < 4; ++rep) {
      int m = lane + rep * 64;
      if (m < MK) sdel[wid][m] = __expf(ld[m]);
    }
  }
  __syncthreads();

#pragma unroll
  for (int rep = 0; rep < 4; ++rep) {
    int kk = lane + rep * 64;
    if (kk < MK - 1) {
      float xK = sxx[wid][kk], dx = sxx[wid][kk+1] - xK;
      float yK = syy[wid][kk], dy = syy[wid][kk+1] - yK;
      float rdx = 1.0f / dx;
      float s_ = dy * rdx;
      float dK = sdel[wid][kk], dK1 = sdel[wid][kk+1];
      ydk8[(t * (MK-1) + kk) * 2 + 0] = make_float4(xK, rdx, yK, dy);
      ydk8[(t * (MK-1) + kk) * 2 + 1] = make_float4(s_, dK, dK1, dK + dK1 - 2.f * s_);
    }
  }
  float xx0v = sxx[wid][0], xxMv = sxx[wid][MK-1];
  if (lane == 0) {
    float scale = (float)GB / (xxMv - xx0v);
    edge[t*2+0] = make_float4(xx0v, syy[wid][0],    sdel[wid][0],    scale);
    edge[t*2+1] = make_float4(xxMv, syy[wid][MK-1], sdel[wid][MK-1], 0.f);
  }
  float bw = (xxMv - xx0v) * (1.f / (float)GB);
#pragma unroll
  for (int i = 0; i < 4; ++i) {
    int g = lane * 4 + i;
    float L = xx0v + (float)g * bw;
    int p = 0;
#pragma unroll
    for (int st = 128; st >= 1; st >>= 1) {
      int cand = p + st;
      if (cand < MK && sxx[wid][cand] < L) p = cand;
    }
    gridb[t * GB + g] = (unsigned char)(p > MK-2 ? MK-2 : p);
  }
}

// ---------------------------------------------------------------------------
// Kernel G: transpose  data[n][dim] -> Xg[k][d][n]. Block = (row rr, 32 samp).
// float4 on both global sides; LDS pad 97 keeps conflicts <=2-way.
// ---------------------------------------------------------------------------
template<int CH>
__global__ __launch_bounds__(256) void gather_kernel(const float* __restrict__ data,
                                                     float* __restrict__ Xg,
                                                     int chunk_base) {
  const int tid = threadIdx.x;
  const int rr = blockIdx.x & 31, tile = blockIdx.x >> 5;
  const int q = (rr + 30) & 31;           // (rr-2) mod 32
  const int nh = q >> 2, kh = q & 3;
  const int n0 = tile * 32;
  __shared__ float sd[32][97];
#pragma unroll
  for (int it = 0; it < 3; ++it) {
    int i = tid + it * 256;               // 768 = 32 samples * 24 float4
    int s = i / 24, f4 = i % 24;
    float4 v = *(const float4*)(data + (size_t)(chunk_base + n0 + s) * NDIM + rr * 96 + f4 * 4);
    sd[s][f4*4+0] = v.x; sd[s][f4*4+1] = v.y; sd[s][f4*4+2] = v.z; sd[s][f4*4+3] = v.w;
  }
  __syncthreads();
#pragma unroll
  for (int it = 0; it < 3; ++it) {
    int o = tid + it * 256;               // 768 = 96 dims * 8 sample-quads
    int s4 = o & 7, p = o >> 3;
    int nw = p / 12, dd = p % 12;
    int c = 12 * nw + 6 + dd; c -= (c >= 96) ? 96 : 0;
    int k = nh * 8 + nw, d = kh * 12 + dd;
    float4 v = make_float4(sd[4*s4+0][c], sd[4*s4+1][c], sd[4*s4+2][c], sd[4*s4+3][c]);
    *(float4*)(Xg + ((size_t)(k * NS + d)) * CH + n0 + 4 * s4) = v;
  }
}

// ---------------------------------------------------------------------------
// Kernel C: per-patch core. Block = (patch k, 256 samples); LDS = xx + edge
// only (40 KB -> 4 blocks/CU). Bucket byte from global (L1); parallel refine;
// 32-B precomputed knot record. In-place Xg -> R.
//
// Phase B j-loop is FULLY unrolled: a partial unroll leaves acc[j]
// runtime-indexed, which demotes the whole acc[48] array to scratch
// (rule #20) -> 3.8x HBM write amplification, VGPR_Count=56, latency-bound.
// Full unroll keeps every acc index compile-time constant -> registers.
// ---------------------------------------------------------------------------
template<int CH>
__global__ __launch_bounds__(256, 4) void core_kernel(
    float* __restrict__ Xg, const float* __restrict__ Qws,
    const float* __restrict__ xxg, const unsigned char* __restrict__ gridb,
    const float4* __restrict__ edge, const float4* __restrict__ ydk8,
    float* __restrict__ partial, int chunk_base) {
  const int tid = threadIdx.x;
  const int k = blockIdx.x & 63, tile = blockIdx.x >> 6;
  const int nl = tile * 256 + tid;
  __shared__ float sxx[NS * MK];
  __shared__ float4 sedge[NS * 2];
  for (int i = tid; i < NS * MK; i += 256) sxx[i] = xxg[k * NS * MK + i];
  if (tid < NS * 2) sedge[tid] = edge[k * NS * 2 + tid];
  __syncthreads();

  float* Xp = Xg + (size_t)k * NS * CH + nl;
  const float* Qk = Qws + k * NS * NS;
  const unsigned char* gk = gridb + (size_t)k * NS * GB;
  const float4* yk = ydk8 + (size_t)k * NS * (MK - 1) * 2;

  // --- phase A: d0 = x . Q ---
  float acc[NS];
#pragma unroll
  for (int j = 0; j < NS; ++j) acc[j] = 0.f;
#pragma unroll 4
  for (int d = 0; d < NS; ++d) {
    float xd = Xp[(size_t)d * CH];
    const float* qrow = Qk + d * NS;
#pragma unroll
    for (int j = 0; j < NS; ++j) acc[j] = fmaf(xd, qrow[j], acc[j]);
  }
  // --- phase B: spline, e = y - d0 ---
  float logsum = 0.f;
#pragma unroll
  for (int j = 0; j < NS; ++j) {
    float v = acc[j];
    float4 e0 = sedge[2*j], e1 = sedge[2*j+1];
    const float* xr = sxx + j * MK;
    int g = (int)((v - e0.x) * e0.w);
    g = g < 0 ? 0 : (g > GB-1 ? GB-1 : g);
    int kk = gk[j * GB + g];
    // parallel refine: monotone xx => independent compares sum correctly
    float xA = xr[imin(kk + 1, MK - 1)];
    float xB = xr[imin(kk + 2, MK - 1)];
    float xC = xr[imin(kk + 3, MK - 1)];
    kk += (int)(kk + 1 <= MK-2 && xA < v) + (int)(kk + 2 <= MK-2 && xB < v)
        + (int)(kk + 3 <= MK-2 && xC < v);
    float4 r0 = yk[(j * (MK-1) + kk) * 2 + 0];    // (xK, rdx, yK, dy)
    float4 r1 = yk[(j * (MK-1) + kk) * 2 + 1];    // (s, dK, dK1, d2s)
    float xi = (v - r0.x) * r0.y;
    xi = fminf(fmaxf(xi, 0.f), 1.f);
    float omxi = 1.f - xi, xi1 = xi * omxi, xi2 = xi * xi;
    float denom = fmaf(r1.w, xi1, r1.x);
    float rden = rcp_fast(denom);
    float y_in = fmaf(r0.w * fmaf(r1.x, xi2, r1.y * xi1), rden, r0.z);
    float d_in = r1.x * r1.x * (r1.z * xi2 + 2.f * r1.x * xi1 + r1.y * omxi * omxi) * (rden * rden);
    bool below = v <= e0.x, above = v > e1.x;
    float yv = below ? fmaf(e0.z, v - e0.x, e0.y)
             : (above ? fmaf(e1.z, v - e1.x, e1.y) : y_in);
    float dd = below ? e0.z : (above ? e1.z : d_in);
    logsum += __logf(dd);
    acc[j] = yv - v;
  }
  partial[k * NSMP + chunk_base + nl] = logsum;
  // --- phase C: R[d] = e . Q[d][:] ---
#pragma unroll 2
  for (int d = 0; d < NS; ++d) {
    const float* qrow = Qk + d * NS;
    float r0 = 0.f, r1 = 0.f, r2 = 0.f, r3 = 0.f;
#pragma unroll
    for (int j = 0; j < NS; j += 4) {
      r0 = fmaf(acc[j+0], qrow[j+0], r0);
      r1 = fmaf(acc[j+1], qrow[j+1], r1);
      r2 = fmaf(acc[j+2], qrow[j+2], r2);
      r3 = fmaf(acc[j+3], qrow[j+3], r3);
    }
    Xp[(size_t)d * CH] = (r0 + r1) + (r2 + r3);
  }
}

// ---------------------------------------------------------------------------
// Kernel S: out[n][dim] = data[n][dim] + untranspose(R).
// ---------------------------------------------------------------------------
template<int CH>
__global__ __launch_bounds__(256) void scatter_kernel(const float* __restrict__ data,
                                                      const float* __restrict__ R,
                                                      float* __restrict__ out,
                                                      int chunk_base) {
  const int tid = threadIdx.x;
  const int rr = blockIdx.x & 31, tile = blockIdx.x >> 5;
  const int q = (rr + 30) & 31;
  const int nh = q >> 2, kh = q & 3;
  const int n0 = tile * 32;
  __shared__ float sd[32][97];
#pragma unroll
  for (int it = 0; it < 3; ++it) {
    int o = tid + it * 256;
    int s4 = o & 7, p = o >> 3;
    int nw = p / 12, dd = p % 12;
    int c = 12 * nw + 6 + dd; c -= (c >= 96) ? 96 : 0;
    int k = nh * 8 + nw, d = kh * 12 + dd;
    float4 v = *(const float4*)(R + ((size_t)(k * NS + d)) * CH + n0 + 4 * s4);
    sd[4*s4+0][c] = v.x; sd[4*s4+1][c] = v.y; sd[4*s4+2][c] = v.z; sd[4*s4+3][c] = v.w;
  }
  __syncthreads();
#pragma unroll
  for (int it = 0; it < 3; ++it) {
    int i = tid + it * 256;
    int s = i / 24, f4 = i % 24;
    size_t off = (size_t)(chunk_base + n0 + s) * NDIM + rr * 96 + f4 * 4;
    float4 v = *(const float4*)(data + off);
    v.x += sd[s][f4*4+0]; v.y += sd[s][f4*4+1];
    v.z += sd[s][f4*4+2]; v.w += sd[s][f4*4+3];
    *(float4*)(out + off) = v;
  }
}

__global__ __launch_bounds__(256) void reduce_kernel(const float* __restrict__ partial,
                                                     float* __restrict__ logj) {
  int n = blockIdx.x * 256 + threadIdx.x;
  float s = 0.f;
#pragma unroll
  for (int k = 0; k < NK; ++k) s += partial[k * NSMP + n];
  logj[n] = s;
}

template<int CH>
static void run_pipeline(const float* data, const float* Araw, const float* x0,
                         const float* logdx, const float* y0, const float* logdy,
                         const float* logderiv, float* out, float* ws,
                         hipStream_t stream) {
  float*         Qws   = ws;                                 // 589,824 B
  float*         xxg   = Qws  + 64 * NS * NS;                // 2,457,600 B
  float4*        ydk8  = (float4*)(xxg + 3072 * MK);         // 19,562,496 B
  float4*        edge  = ydk8 + 3072 * (MK - 1) * 2;         // 98,304 B
  unsigned char* gridb = (unsigned char*)(edge + 3072 * 2);  // 786,432 B
  float*         Xg    = (float*)(gridb + 3072 * GB);        // 12288*CH B
  float*         partial = Xg + (size_t)NK * NS * CH;        // 2,097,152 B

  qr_kernel<<<64, 64, 0, stream>>>(Araw, Qws);
  knots_kernel<<<768, 256, 0, stream>>>(x0, logdx, y0, logdy, logderiv,
                                        xxg, ydk8, edge, gridb);
  for (int c = 0; c < NSMP / CH; ++c) {
    const int base = c * CH;
    gather_kernel<CH> <<<CH,     256, 0, stream>>>(data, Xg, base);
    core_kernel<CH>   <<<CH / 4, 256, 0, stream>>>(Xg, Qws, xxg, gridb, edge, ydk8,
                                                   partial, base);
    scatter_kernel<CH><<<CH,     256, 0, stream>>>(data, Xg, out, base);
  }
  reduce_kernel<<<32, 256, 0, stream>>>(partial, out + (size_t)NSMP * NDIM);
}

extern "C" void kernel_launch(void* const* d_in, const int* in_sizes, int n_in,
                              void* d_out, int out_size, void* d_ws, size_t ws_size,
                              hipStream_t stream) {
  const float* data     = (const float*)d_in[0];
  const float* Araw     = (const float*)d_in[1];
  const float* x0       = (const float*)d_in[2];
  const float* logdx    = (const float*)d_in[3];
  const float* y0       = (const float*)d_in[4];
  const float* logdy    = (const float*)d_in[5];
  const float* logderiv = (const float*)d_in[6];
  float* out = (float*)d_out;
  float* ws  = (float*)d_ws;

  const size_t fixed = 589824 + 2457600 + 19562496 + 98304 + 786432 + 2097152;
  if (ws_size >= fixed + (size_t)12288 * 8192)
    run_pipeline<8192>(data, Araw, x0, logdx, y0, logdy, logderiv, out, ws, stream);
  else if (ws_size >= fixed + (size_t)12288 * 4096)
    run_pipeline<4096>(data, Araw, x0, logdx, y0, logdy, logderiv, out, ws, stream);
  else
    run_pipeline<2048>(data, Araw, x0, logdx, y0, logdy, logderiv, out, ws, stream);
}

// Round 2
// 533.570 us; speedup vs baseline: 2.4297x; 2.4297x over previous
//
#include <hip/hip_runtime.h>

#define NSMP  8192
#define NDIM  3072
#define NK    64
#define NS    48
#define MK    200   // knots per transform
#define GB    256   // lookup-grid buckets

__device__ __forceinline__ float rcp_fast(float x) { return __builtin_amdgcn_rcpf(x); }
__device__ __forceinline__ int imin(int a, int b) { return a < b ? a : b; }

// ---------------------------------------------------------------------------
// Kernel 1: 64 independent 48x48 QR factorizations (modified Gram-Schmidt).
// ---------------------------------------------------------------------------
__global__ __launch_bounds__(64) void qr_kernel(const float* __restrict__ Araw,
                                                float* __restrict__ Qws) {
  const int k = blockIdx.x;
  const int lane = threadIdx.x;
  const float* Ak = Araw + k * NS * NS;
  float col[NS];
#pragma unroll
  for (int r = 0; r < NS; ++r)
    col[r] = (lane < NS) ? Ak[r * NS + lane] : 0.f;

  for (int j = 0; j < NS; ++j) {
    float q[NS];
#pragma unroll
    for (int r = 0; r < NS; ++r)
      q[r] = __int_as_float(__builtin_amdgcn_readlane(__float_as_int(col[r]), j));
    float n0 = 0.f, n1 = 0.f, n2 = 0.f, n3 = 0.f;
#pragma unroll
    for (int r = 0; r < NS; r += 4) {
      n0 = fmaf(q[r+0], q[r+0], n0); n1 = fmaf(q[r+1], q[r+1], n1);
      n2 = fmaf(q[r+2], q[r+2], n2); n3 = fmaf(q[r+3], q[r+3], n3);
    }
    float rinv = 1.0f / sqrtf((n0 + n1) + (n2 + n3));
#pragma unroll
    for (int r = 0; r < NS; ++r) q[r] *= rinv;
    if (lane == j) {
#pragma unroll
      for (int r = 0; r < NS; ++r) col[r] = q[r];
    } else if (lane > j && lane < NS) {
      float d0 = 0.f, d1 = 0.f, d2 = 0.f, d3 = 0.f;
#pragma unroll
      for (int r = 0; r < NS; r += 4) {
        d0 = fmaf(q[r+0], col[r+0], d0); d1 = fmaf(q[r+1], col[r+1], d1);
        d2 = fmaf(q[r+2], col[r+2], d2); d3 = fmaf(q[r+3], col[r+3], d3);
      }
      float dt = (d0 + d1) + (d2 + d3);
#pragma unroll
      for (int r = 0; r < NS; ++r) col[r] = fmaf(-dt, q[r], col[r]);
    }
  }
  if (lane < NS) {
    float* Qk = Qws + k * NS * NS;
#pragma unroll
    for (int r = 0; r < NS; ++r) Qk[r * NS + lane] = col[r];
  }
}

// ---------------------------------------------------------------------------
// Kernel 2: knot tables. One wave per transform row t.
//  xxg[t][0..199]    knot x positions
//  ydk8[t][kk]       2x float4: (xK, 1/dx, yK, dy), (s, dK, dK1, dK+dK1-2s)
//  edge[t*2+{0,1}]   (xx0,yy0,del0,scale), (xxM,yyM,delM,0)
//  gridb[t][g] u8    start interval for bucket g
// ---------------------------------------------------------------------------
__global__ __launch_bounds__(256) void knots_kernel(
    const float* __restrict__ x0, const float* __restrict__ logdx,
    const float* __restrict__ y0, const float* __restrict__ logdy,
    const float* __restrict__ logderiv,
    float* __restrict__ xxg, float4* __restrict__ ydk8,
    float4* __restrict__ edge, unsigned char* __restrict__ gridb) {
  const int wid = threadIdx.x >> 6, lane = threadIdx.x & 63;
  const int t = blockIdx.x * 4 + wid;
  __shared__ float sxx[4][MK], syy[4][MK], sdel[4][MK];

  {
    const float* row = logdx + t * (MK - 1);
    int i0 = lane * 4;
    float e0 = (i0 + 0 < MK - 1) ? __expf(row[i0 + 0]) : 0.f;
    float e1 = (i0 + 1 < MK - 1) ? __expf(row[i0 + 1]) : 0.f;
    float e2 = (i0 + 2 < MK - 1) ? __expf(row[i0 + 2]) : 0.f;
    float e3 = (i0 + 3 < MK - 1) ? __expf(row[i0 + 3]) : 0.f;
    float p0 = e0, p1 = p0 + e1, p2 = p1 + e2, p3 = p2 + e3;
    float incl = p3;
#pragma unroll
    for (int off = 1; off < 64; off <<= 1) {
      float u = __shfl_up(incl, off, 64);
      if (lane >= off) incl += u;
    }
    float xv = x0[t];
    float base = xv + (incl - p3);
    float* xrow = xxg + t * MK;
    if (lane == 0) { xrow[0] = xv; sxx[wid][0] = xv; }
    if (i0 + 0 < MK - 1) { xrow[1+i0+0] = base + p0; sxx[wid][1+i0+0] = base + p0; }
    if (i0 + 1 < MK - 1) { xrow[1+i0+1] = base + p1; sxx[wid][1+i0+1] = base + p1; }
    if (i0 + 2 < MK - 1) { xrow[1+i0+2] = base + p2; sxx[wid][1+i0+2] = base + p2; }
    if (i0 + 3 < MK - 1) { xrow[1+i0+3] = base + p3; sxx[wid][1+i0+3] = base + p3; }
  }
  {
    const float* row = logdy + t * (MK - 1);
    int i0 = lane * 4;
    float e0 = (i0 + 0 < MK - 1) ? __expf(row[i0 + 0]) : 0.f;
    float e1 = (i0 + 1 < MK - 1) ? __expf(row[i0 + 1]) : 0.f;
    float e2 = (i0 + 2 < MK - 1) ? __expf(row[i0 + 2]) : 0.f;
    float e3 = (i0 + 3 < MK - 1) ? __expf(row[i0 + 3]) : 0.f;
    float p0 = e0, p1 = p0 + e1, p2 = p1 + e2, p3 = p2 + e3;
    float incl = p3;
#pragma unroll
    for (int off = 1; off < 64; off <<= 1) {
      float u = __shfl_up(incl, off, 64);
      if (lane >= off) incl += u;
    }
    float yv = y0[t];
    float base = yv + (incl - p3);
    if (lane == 0) syy[wid][0] = yv;
    if (i0 + 0 < MK - 1) syy[wid][1+i0+0] = base + p0;
    if (i0 + 1 < MK - 1) syy[wid][1+i0+1] = base + p1;
    if (i0 + 2 < MK - 1) syy[wid][1+i0+2] = base + p2;
    if (i0 + 3 < MK - 1) syy[wid][1+i0+3] = base + p3;
  }
  {
    const float* ld = logderiv + t * MK;
#pragma unroll
    for (int rep = 0; rep < 4; ++rep) {
      int m = lane + rep * 64;
      if (m < MK) sdel[wid][m] = __expf(ld[m]);
    }
  }
  __syncthreads();

#pragma unroll
  for (int rep = 0; rep < 4; ++rep) {
    int kk = lane + rep * 64;
    if (kk < MK - 1) {
      float xK = sxx[wid][kk], dx = sxx[wid][kk+1] - xK;
      float yK = syy[wid][kk], dy = syy[wid][kk+1] - yK;
      float rdx = 1.0f / dx;
      float s_ = dy * rdx;
      float dK = sdel[wid][kk], dK1 = sdel[wid][kk+1];
      ydk8[(t * (MK-1) + kk) * 2 + 0] = make_float4(xK, rdx, yK, dy);
      ydk8[(t * (MK-1) + kk) * 2 + 1] = make_float4(s_, dK, dK1, dK + dK1 - 2.f * s_);
    }
  }
  float xx0v = sxx[wid][0], xxMv = sxx[wid][MK-1];
  if (lane == 0) {
    float scale = (float)GB / (xxMv - xx0v);
    edge[t*2+0] = make_float4(xx0v, syy[wid][0],    sdel[wid][0],    scale);
    edge[t*2+1] = make_float4(xxMv, syy[wid][MK-1], sdel[wid][MK-1], 0.f);
  }
  float bw = (xxMv - xx0v) * (1.f / (float)GB);
#pragma unroll
  for (int i = 0; i < 4; ++i) {
    int g = lane * 4 + i;
    float L = xx0v + (float)g * bw;
    int p = 0;
#pragma unroll
    for (int st = 128; st >= 1; st >>= 1) {
      int cand = p + st;
      if (cand < MK && sxx[wid][cand] < L) p = cand;
    }
    gridb[t * GB + g] = (unsigned char)(p > MK-2 ? MK-2 : p);
  }
}

// ---------------------------------------------------------------------------
// Kernel G: transpose  data[n][dim] -> Xg[k][d][n]. Block = (row rr, 32 samp).
// float4 on both global sides; LDS pad 97 keeps conflicts <=2-way.
// ---------------------------------------------------------------------------
template<int CH>
__global__ __launch_bounds__(256) void gather_kernel(const float* __restrict__ data,
                                                     float* __restrict__ Xg,
                                                     int chunk_base) {
  const int tid = threadIdx.x;
  const int rr = blockIdx.x & 31, tile = blockIdx.x >> 5;
  const int q = (rr + 30) & 31;           // (rr-2) mod 32
  const int nh = q >> 2, kh = q & 3;
  const int n0 = tile * 32;
  __shared__ float sd[32][97];
#pragma unroll
  for (int it = 0; it < 3; ++it) {
    int i = tid + it * 256;               // 768 = 32 samples * 24 float4
    int s = i / 24, f4 = i % 24;
    float4 v = *(const float4*)(data + (size_t)(chunk_base + n0 + s) * NDIM + rr * 96 + f4 * 4);
    sd[s][f4*4+0] = v.x; sd[s][f4*4+1] = v.y; sd[s][f4*4+2] = v.z; sd[s][f4*4+3] = v.w;
  }
  __syncthreads();
#pragma unroll
  for (int it = 0; it < 3; ++it) {
    int o = tid + it * 256;               // 768 = 96 dims * 8 sample-quads
    int s4 = o & 7, p = o >> 3;
    int nw = p / 12, dd = p % 12;
    int c = 12 * nw + 6 + dd; c -= (c >= 96) ? 96 : 0;
    int k = nh * 8 + nw, d = kh * 12 + dd;
    float4 v = make_float4(sd[4*s4+0][c], sd[4*s4+1][c], sd[4*s4+2][c], sd[4*s4+3][c]);
    *(float4*)(Xg + ((size_t)(k * NS + d)) * CH + n0 + 4 * s4) = v;
  }
}

// ---------------------------------------------------------------------------
// Kernel C: per-patch core, 4-way j-sliced. Block = 512 thr = 8 waves =
// (4 slices) x (2 sample-halves) x 64 lanes, covering 128 samples of one k.
// Per-thread arrays are 12 wide (fully unrolled, static indices) so they
// stay in VGPRs -- the 48-wide variants were demoted to scratch (round 0/1:
// 0.3-1.6 GB of spill traffic). x staged in LDS [128][49] (odd pad, <=2-way
// banks), e overwrites it after a barrier. Q read at wave-uniform addresses
// (slice in SGPR via readfirstlane) -> s_load broadcast. Spline refine reads
// global xxg (L2-resident 2.4 MB) instead of staging 38.4 KB sxx per block.
// ---------------------------------------------------------------------------
template<int CH>
__global__ __launch_bounds__(512, 4) void core_kernel(
    float* __restrict__ Xg, const float* __restrict__ Qws,
    const float* __restrict__ xxg, const unsigned char* __restrict__ gridb,
    const float4* __restrict__ edge, const float4* __restrict__ ydk8,
    float* __restrict__ partial, int chunk_base) {
  const int tid = threadIdx.x;
  const int k = blockIdx.x & 63, tile = blockIdx.x >> 6;
  const int n0 = tile * 128;
  const int lane = tid & 63;
  const int slice = __builtin_amdgcn_readfirstlane(tid >> 7);  // 0..3, SGPR
  const int shalf = (tid >> 6) & 1;
  const int s = shalf * 64 + lane;                             // 0..127

  __shared__ float xs[128][49];   // x, then reused for e
  __shared__ float lp[4][128];    // per-slice logsum partials

  const float* Qk = Qws + k * NS * NS;

  // ---- stage x: Xg[k][d][n0+s] -> xs[s][d] (coalesced global, <=2-way LDS)
  {
    const int sS = tid & 127, dq = tid >> 7;
    const float* src = Xg + (size_t)k * NS * CH + n0 + sS;
#pragma unroll
    for (int r = 0; r < 12; ++r) {
      int d = dq * 12 + r;
      xs[sS][d] = src[(size_t)d * CH];
    }
  }
  __syncthreads();

  // ---- phase A: acc[12] = x . Q[:, slice*12 .. slice*12+11] ----
  float acc[12];
#pragma unroll
  for (int j = 0; j < 12; ++j) acc[j] = 0.f;
  {
    const float* qbase = Qk + slice * 12;
#pragma unroll 4
    for (int d = 0; d < NS; ++d) {
      float xd = xs[s][d];
      const float* q = qbase + d * NS;
#pragma unroll
      for (int j = 0; j < 12; ++j) acc[j] = fmaf(xd, q[j], acc[j]);
    }
  }

  // ---- phase B: spline on 12 values, e = y - d0 (registers only) ----
  float logsum = 0.f;
  {
    const unsigned char* gk = gridb + (size_t)k * NS * GB;
    const float4* yk = ydk8 + (size_t)k * NS * (MK - 1) * 2;
    const float4* ek = edge + (size_t)k * NS * 2;
    const float* xk = xxg + (size_t)k * NS * MK;
#pragma unroll
    for (int jj = 0; jj < 12; ++jj) {
      const int jg = slice * 12 + jj;
      float v = acc[jj];
      float4 e0 = ek[2*jg], e1 = ek[2*jg+1];
      int g = (int)((v - e0.x) * e0.w);
      g = g < 0 ? 0 : (g > GB-1 ? GB-1 : g);
      int kk = gk[jg * GB + g];
      const float* xr = xk + jg * MK;
      // parallel refine: monotone xx => independent compares sum correctly
      float xA = xr[imin(kk + 1, MK - 1)];
      float xB = xr[imin(kk + 2, MK - 1)];
      float xC = xr[imin(kk + 3, MK - 1)];
      kk += (int)(kk + 1 <= MK-2 && xA < v) + (int)(kk + 2 <= MK-2 && xB < v)
          + (int)(kk + 3 <= MK-2 && xC < v);
      float4 r0 = yk[(jg * (MK-1) + kk) * 2 + 0];   // (xK, rdx, yK, dy)
      float4 r1 = yk[(jg * (MK-1) + kk) * 2 + 1];   // (s, dK, dK1, d2s)
      float xi = (v - r0.x) * r0.y;
      xi = fminf(fmaxf(xi, 0.f), 1.f);
      float omxi = 1.f - xi, xi1 = xi * omxi, xi2 = xi * xi;
      float denom = fmaf(r1.w, xi1, r1.x);
      float rden = rcp_fast(denom);
      float y_in = fmaf(r0.w * fmaf(r1.x, xi2, r1.y * xi1), rden, r0.z);
      float d_in = r1.x * r1.x * (r1.z * xi2 + 2.f * r1.x * xi1 + r1.y * omxi * omxi) * (rden * rden);
      bool below = v <= e0.x, above = v > e1.x;
      float yv = below ? fmaf(e0.z, v - e0.x, e0.y)
               : (above ? fmaf(e1.z, v - e1.x, e1.y) : y_in);
      float dd = below ? e0.z : (above ? e1.z : d_in);
      logsum += __logf(dd);
      acc[jj] = yv - v;
    }
  }

  // ---- publish e into xs (reuse) + logsum partials ----
  __syncthreads();   // all phase-A reads of xs complete
#pragma unroll
  for (int jj = 0; jj < 12; ++jj) xs[s][slice * 12 + jj] = acc[jj];
  lp[slice][s] = logsum;
  __syncthreads();

  if (tid < 128) {
    float t = lp[0][tid] + lp[1][tid] + lp[2][tid] + lp[3][tid];
    partial[(size_t)k * NSMP + chunk_base + n0 + tid] = t;
  }

  // ---- phase C: R[slice*12+dd] = e . Q[row][:]  (in-place Xg -> R) ----
  float r[12];
#pragma unroll
  for (int d = 0; d < 12; ++d) r[d] = 0.f;
  {
    const float* qrow = Qk + (slice * 12) * NS;
#pragma unroll 2
    for (int j = 0; j < NS; ++j) {
      float ej = xs[s][j];
#pragma unroll
      for (int d = 0; d < 12; ++d) r[d] = fmaf(ej, qrow[d * NS + j], r[d]);
    }
  }
  float* dst = Xg + ((size_t)k * NS + slice * 12) * CH + n0 + s;
#pragma unroll
  for (int d = 0; d < 12; ++d) dst[(size_t)d * CH] = r[d];
}

// ---------------------------------------------------------------------------
// Kernel S: out[n][dim] = data[n][dim] + untranspose(R).
// ---------------------------------------------------------------------------
template<int CH>
__global__ __launch_bounds__(256) void scatter_kernel(const float* __restrict__ data,
                                                      const float* __restrict__ R,
                                                      float* __restrict__ out,
                                                      int chunk_base) {
  const int tid = threadIdx.x;
  const int rr = blockIdx.x & 31, tile = blockIdx.x >> 5;
  const int q = (rr + 30) & 31;
  const int nh = q >> 2, kh = q & 3;
  const int n0 = tile * 32;
  __shared__ float sd[32][97];
#pragma unroll
  for (int it = 0; it < 3; ++it) {
    int o = tid + it * 256;
    int s4 = o & 7, p = o >> 3;
    int nw = p / 12, dd = p % 12;
    int c = 12 * nw + 6 + dd; c -= (c >= 96) ? 96 : 0;
    int k = nh * 8 + nw, d = kh * 12 + dd;
    float4 v = *(const float4*)(R + ((size_t)(k * NS + d)) * CH + n0 + 4 * s4);
    sd[4*s4+0][c] = v.x; sd[4*s4+1][c] = v.y; sd[4*s4+2][c] = v.z; sd[4*s4+3][c] = v.w;
  }
  __syncthreads();
#pragma unroll
  for (int it = 0; it < 3; ++it) {
    int i = tid + it * 256;
    int s = i / 24, f4 = i % 24;
    size_t off = (size_t)(chunk_base + n0 + s) * NDIM + rr * 96 + f4 * 4;
    float4 v = *(const float4*)(data + off);
    v.x += sd[s][f4*4+0]; v.y += sd[s][f4*4+1];
    v.z += sd[s][f4*4+2]; v.w += sd[s][f4*4+3];
    *(float4*)(out + off) = v;
  }
}

__global__ __launch_bounds__(256) void reduce_kernel(const float* __restrict__ partial,
                                                     float* __restrict__ logj) {
  int n = blockIdx.x * 256 + threadIdx.x;
  float s = 0.f;
#pragma unroll
  for (int k = 0; k < NK; ++k) s += partial[k * NSMP + n];
  logj[n] = s;
}

template<int CH>
static void run_pipeline(const float* data, const float* Araw, const float* x0,
                         const float* logdx, const float* y0, const float* logdy,
                         const float* logderiv, float* out, float* ws,
                         hipStream_t stream) {
  float*         Qws   = ws;                                 // 589,824 B
  float*         xxg   = Qws  + 64 * NS * NS;                // 2,457,600 B
  float4*        ydk8  = (float4*)(xxg + 3072 * MK);         // 19,562,496 B
  float4*        edge  = ydk8 + 3072 * (MK - 1) * 2;         // 98,304 B
  unsigned char* gridb = (unsigned char*)(edge + 3072 * 2);  // 786,432 B
  float*         Xg    = (float*)(gridb + 3072 * GB);        // 12288*CH B
  float*         partial = Xg + (size_t)NK * NS * CH;        // 2,097,152 B

  qr_kernel<<<64, 64, 0, stream>>>(Araw, Qws);
  knots_kernel<<<768, 256, 0, stream>>>(x0, logdx, y0, logdy, logderiv,
                                        xxg, ydk8, edge, gridb);
  for (int c = 0; c < NSMP / CH; ++c) {
    const int base = c * CH;
    gather_kernel<CH> <<<CH,          256, 0, stream>>>(data, Xg, base);
    core_kernel<CH>   <<<64*(CH/128), 512, 0, stream>>>(Xg, Qws, xxg, gridb, edge, ydk8,
                                                        partial, base);
    scatter_kernel<CH><<<CH,          256, 0, stream>>>(data, Xg, out, base);
  }
  reduce_kernel<<<32, 256, 0, stream>>>(partial, out + (size_t)NSMP * NDIM);
}

extern "C" void kernel_launch(void* const* d_in, const int* in_sizes, int n_in,
                              void* d_out, int out_size, void* d_ws, size_t ws_size,
                              hipStream_t stream) {
  const float* data     = (const float*)d_in[0];
  const float* Araw     = (const float*)d_in[1];
  const float* x0       = (const float*)d_in[2];
  const float* logdx    = (const float*)d_in[3];
  const float* y0       = (const float*)d_in[4];
  const float* logdy    = (const float*)d_in[5];
  const float* logderiv = (const float*)d_in[6];
  float* out = (float*)d_out;
  float* ws  = (float*)d_ws;

  const size_t fixed = 589824 + 2457600 + 19562496 + 98304 + 786432 + 2097152;
  if (ws_size >= fixed + (size_t)12288 * 8192)
    run_pipeline<8192>(data, Araw, x0, logdx, y0, logdy, logderiv, out, ws, stream);
  else if (ws_size >= fixed + (size_t)12288 * 4096)
    run_pipeline<4096>(data, Araw, x0, logdx, y0, logdy, logderiv, out, ws, stream);
  else
    run_pipeline<2048>(data, Araw, x0, logdx, y0, logdy, logderiv, out, ws, stream);
}